// Round 4
// baseline (152.620 us; speedup 1.0000x reference)
//
#include <hip/hip_runtime.h>

// B=16, C=256, O=256, H=W=64, T_DIM=512, E=4, K=3
typedef __bf16 bf16x8 __attribute__((ext_vector_type(8)));
typedef float f32x4 __attribute__((ext_vector_type(4)));

__device__ __forceinline__ unsigned short f2bf(float f) {
  union { float f; unsigned int u; } v;
  v.f = f;
  unsigned int r = v.u + 0x7FFFu + ((v.u >> 16) & 1u);  // RNE
  return (unsigned short)(r >> 16);
}

__device__ __forceinline__ void load_lds16(const void* g, void* l) {
  __builtin_amdgcn_global_load_lds(
      (__attribute__((address_space(1))) void*)(void*)g,
      (__attribute__((address_space(3))) void*)l, 16, 0, 0);
}

// ---------- transpose + pad + pooled partials ----------
// x[b][c][h][w] fp32 -> xTpad[b][hp=h+1][wp=w+1][c] bf16 (zero borders)
// part[(b*64+h)*256 + c] = sum_w x[b][c][h][w]
__global__ void transpose_kernel(const float* __restrict__ x, unsigned short* __restrict__ xTpad,
                                 float* __restrict__ part) {
  int bid = blockIdx.x;
  int b = bid / 66, hp = bid % 66;
  unsigned short* rowbase = xTpad + ((size_t)(b * 66 + hp)) * 66 * 256;
  int t = threadIdx.x;
  if (hp == 0 || hp == 65) {   // zero border rows: 66*256 ushorts = 2112 uint4
    uint4 z = make_uint4(0u, 0u, 0u, 0u);
    for (int i = t; i < 2112; i += 256) ((uint4*)rowbase)[i] = z;
    return;
  }
  int h = hp - 1;
  __shared__ unsigned short lds[64][264];   // [w][c], 528B rows (16B aligned)
  __shared__ float psum[256];
  const float* xb = x + ((size_t)b * 256 * 64 + h) * 64;
  int lane = t & 63;
  #pragma unroll
  for (int g = 0; g < 16; ++g) {
    int c = g * 16 + (t >> 4);
    int w0 = (t & 15) * 4;
    float4 v = *(const float4*)&xb[(size_t)c * 4096 + w0];
    lds[w0 + 0][c] = f2bf(v.x);
    lds[w0 + 1][c] = f2bf(v.y);
    lds[w0 + 2][c] = f2bf(v.z);
    lds[w0 + 3][c] = f2bf(v.w);
    float s = v.x + v.y + v.z + v.w;
    s += __shfl_xor(s, 1); s += __shfl_xor(s, 2);
    s += __shfl_xor(s, 4); s += __shfl_xor(s, 8);
    if ((lane & 15) == 0) psum[c] = s;   // unique c per (g, 16-lane group)
  }
  __syncthreads();
  // interior rows wp=1..64, plus zero wp=0,65
  #pragma unroll
  for (int p = 0; p < 8; ++p) {
    int w = p * 8 + (t >> 5);
    int seg = t & 31;
    uint4 u = *(const uint4*)&lds[w][seg * 8];
    *(uint4*)&rowbase[(w + 1) * 256 + seg * 8] = u;
  }
  if (t < 64) {
    uint4 z = make_uint4(0u, 0u, 0u, 0u);
    int row = (t >> 5) ? 65 : 0;
    *(uint4*)&rowbase[row * 256 + (t & 31) * 8] = z;
  }
  if (t < 256) part[((size_t)b * 64 + h) * 256 + t] = psum[t];
}

// ---------- router (fp32 exact), 512 threads: q-dot and k/v-dots split ----------
__global__ void router_kernel(
    const float* __restrict__ time_emb, const float* __restrict__ part,
    const float* __restrict__ Wq, const float* __restrict__ bq,
    const float* __restrict__ Wk, const float* __restrict__ bk,
    const float* __restrict__ Wv, const float* __restrict__ bv,
    const float* __restrict__ Wm1, const float* __restrict__ bm1,
    const float* __restrict__ Wm2, const float* __restrict__ bm2,
    const float* __restrict__ Wc, const float* __restrict__ bc,
    const float* __restrict__ expert_b,
    float* __restrict__ rw_out, float* __restrict__ beff_out) {
  int b = blockIdx.x, tid = threadIdx.x;
  int t = tid & 255;
  __shared__ float te[512], pl[256], qs[256], xa[256], m1s[64], xms[256], rws[4];
  te[tid] = time_emb[b * 512 + tid];
  if (tid < 256) {
    float s = 0.f;
    const float* pp = part + (size_t)b * 16384 + tid;
    for (int hh = 0; hh < 64; ++hh) s += pp[hh * 256];
    pl[tid] = s * (1.0f / 4096.0f);
  }
  __syncthreads();
  if (tid < 256) {
    float q = bq[t];
    const float4* wq4 = (const float4*)(Wq + (size_t)t * 512);
    #pragma unroll 4
    for (int i = 0; i < 128; ++i) {
      float4 w4 = wq4[i];
      q += w4.x * te[i*4] + w4.y * te[i*4+1] + w4.z * te[i*4+2] + w4.w * te[i*4+3];
    }
    qs[t] = q;
  } else {
    float k = bk[t], v = bv[t];
    const float4* wk4 = (const float4*)(Wk + (size_t)t * 256);
    const float4* wv4 = (const float4*)(Wv + (size_t)t * 256);
    #pragma unroll 4
    for (int i = 0; i < 64; ++i) {
      float4 a4 = wk4[i], b4 = wv4[i];
      float p0 = pl[i*4], p1 = pl[i*4+1], p2 = pl[i*4+2], p3 = pl[i*4+3];
      k += a4.x * p0 + a4.y * p1 + a4.z * p2 + a4.w * p3;
      v += b4.x * p0 + b4.y * p1 + b4.z * p2 + b4.w * p3;
    }
    // reuse m1s/xms space to pass k,v? keep simple: dedicated smem
    xa[t] = k;       // temporarily store k
    xms[t] = v;      // temporarily store v
  }
  __syncthreads();
  if (tid < 256) {
    float k = xa[t], v = xms[t];
    float attn = 1.0f / (1.0f + expf(-(qs[t] * k)));
    float xatt = v * attn;
    qs[t] = xatt;    // qs now holds x_att
  }
  __syncthreads();
  if (tid < 64) {
    float s = bm1[tid];
    const float4* w1 = (const float4*)(Wm1 + (size_t)tid * 256);
    #pragma unroll 4
    for (int i = 0; i < 64; ++i) {
      float4 w4 = w1[i];
      s += w4.x * qs[i*4] + w4.y * qs[i*4+1] + w4.z * qs[i*4+2] + w4.w * qs[i*4+3];
    }
    m1s[tid] = 0.5f * s * (1.0f + erff(s * 0.7071067811865476f));
  }
  __syncthreads();
  if (tid < 256) {
    float hsum = bm2[t];
    const float* w2 = Wm2 + (size_t)t * 64;
    for (int j = 0; j < 64; ++j) hsum += m1s[j] * w2[j];
    xms[t] = qs[t] + hsum;
  }
  __syncthreads();
  if (tid < 4) {
    float s = bc[tid];
    const float* wc = Wc + (size_t)tid * 256;
    for (int i = 0; i < 256; ++i) s += xms[i] * wc[i];
    float r = tanhf(s);
    rws[tid] = r;
    rw_out[b * 4 + tid] = r;
  }
  __syncthreads();
  if (tid < 256) {
    float be = 0.f;
    #pragma unroll
    for (int e = 0; e < 4; ++e) be += rws[e] * expert_b[e * 256 + t];
    beff_out[b * 256 + t] = be;
  }
}

// ---------- expert mix -> wmix[b][o][k], k = tap*256 + c ----------
__global__ void wmix_kernel(const float* __restrict__ ew, const float* __restrict__ rw,
                            unsigned short* __restrict__ wmix) {
  int o = blockIdx.x, t = threadIdx.x;
  __shared__ float lew[4][2304];
  __shared__ float rsh[64];
  if (t < 64) rsh[t] = rw[t];
  #pragma unroll
  for (int e = 0; e < 4; ++e) {
    const float* s = ew + ((size_t)e * 256 + o) * 2304;
    #pragma unroll
    for (int j = 0; j < 9; ++j) lew[e][j * 256 + t] = s[j * 256 + t];
  }
  __syncthreads();
  float wv[4][9];
  #pragma unroll
  for (int e = 0; e < 4; ++e)
    #pragma unroll
    for (int tt = 0; tt < 9; ++tt) wv[e][tt] = lew[e][t * 9 + tt];
  for (int b = 0; b < 16; ++b) {
    float r0 = rsh[b*4], r1 = rsh[b*4+1], r2 = rsh[b*4+2], r3 = rsh[b*4+3];
    unsigned short* wo = wmix + ((size_t)b * 256 + o) * 2304 + t;
    #pragma unroll
    for (int tt = 0; tt < 9; ++tt) {
      float m = r0 * wv[0][tt] + r1 * wv[1][tt] + r2 * wv[2][tt] + r3 * wv[3][tt];
      wo[tt * 256] = f2bf(m);
    }
  }
}

// ---------- conv: 256x256x2304 GEMM per sample, 8-phase counted-vmcnt ----------
// 512 thr = 8 waves (4M x 2N). All 8 stagings for tile t+1 issue at tile t P1
// (FIFO: A0..A3,B00,B10,B01,B11); vmcnt(8)@P2 guards old B01/B11,
// vmcnt(2)@P4-end guards next tile's P1 needs. P4 MFMA is register-only.
__global__ __launch_bounds__(512, 2) void conv_kernel(
    const unsigned short* __restrict__ xT, const unsigned short* __restrict__ wmix,
    const float* __restrict__ beff, float* __restrict__ out) {
  __shared__ unsigned short As[2][16384];
  __shared__ unsigned short Bs[2][16384];
  int bid = blockIdx.x;
  int b = ((bid & 7) << 1) | ((bid >> 7) & 1);   // same b -> same XCD
  int nt = (bid >> 3) & 15;
  int h0 = nt << 2;
  int tid = threadIdx.x;
  int wid = tid >> 6, lane = tid & 63;
  int lm = lane & 15, lg = lane >> 4;
  int wm = wid >> 1, wn = wid & 1;   // 4M x 2N wave grid

  const unsigned short* wmb = wmix + (size_t)b * 256 * 2304;
  const unsigned short* xTb = xT + (size_t)b * 66 * 66 * 256;

  // staging lane constants (pre-swizzled source slot)
  int lr = lane >> 3;                   // row-in-8
  int slot_g = (lane & 7) ^ lr;
  int a_lane = lr * 2304 + slot_g * 8;  // elements
  int b_lane = lr * 256 + slot_g * 8;

  // read-side swizzled k-slot offsets (ushorts)
  int sw0 = ((0 + lg) ^ (lm & 7)) * 8;
  int sw1 = ((4 + lg) ^ (lm & 7)) * 8;

  auto stA = [&](int buf, int s, int u) {
    const unsigned short* src = wmb + (size_t)(u * 64 + wid * 8) * 2304 + s * 64 + a_lane;
    load_lds16(src, &As[buf][(u * 64 + wid * 8) * 64]);
  };
  auto stB = [&](int buf, int s, int bh, int rq) {
    int tap = s >> 2;
    int kh = tap / 3, kw = tap - kh * 3;
    int c0 = (s & 3) * 64;
    const unsigned short* src =
        xTb + (size_t)((h0 + bh * 2 + rq + kh) * 66 + wid * 8 + kw) * 256 + c0 + b_lane;
    load_lds16(src, &Bs[buf][(bh * 128 + rq * 64 + wid * 8) * 64]);
  };

  f32x4 acc[4][8];
  #pragma unroll
  for (int mf = 0; mf < 4; ++mf)
    #pragma unroll
    for (int nf = 0; nf < 8; ++nf)
      acc[mf][nf] = (f32x4){0.f, 0.f, 0.f, 0.f};

  // prologue: stage tile 0 in FIFO order (B01,B11 last)
  stA(0, 0, 0); stA(0, 0, 1); stA(0, 0, 2); stA(0, 0, 3);
  stB(0, 0, 0, 0); stB(0, 0, 1, 0);
  stB(0, 0, 0, 1); stB(0, 0, 1, 1);
  asm volatile("s_waitcnt vmcnt(2)" ::: "memory");
  __builtin_amdgcn_s_barrier();

  auto do_tile = [&](int t, int BUF) __attribute__((always_inline)) {
    bool st = (t < 35);
    int s = t + 1;
    bf16x8 a01[2][2], a23[2][2], bA[4][2], bB[4][2];
    // ---- P1: read A mf0-1 + B rows of own half; issue ALL 8 stagings for t+1
    #pragma unroll
    for (int mf = 0; mf < 2; ++mf) {
      a01[mf][0] = *(const bf16x8*)&As[BUF][(wm * 64 + mf * 16 + lm) * 64 + sw0];
      a01[mf][1] = *(const bf16x8*)&As[BUF][(wm * 64 + mf * 16 + lm) * 64 + sw1];
    }
    #pragma unroll
    for (int nf = 0; nf < 4; ++nf) {
      bA[nf][0] = *(const bf16x8*)&Bs[BUF][(wn * 128 + nf * 16 + lm) * 64 + sw0];
      bA[nf][1] = *(const bf16x8*)&Bs[BUF][(wn * 128 + nf * 16 + lm) * 64 + sw1];
    }
    if (st) {
      stA(BUF ^ 1, s, 0); stA(BUF ^ 1, s, 1); stA(BUF ^ 1, s, 2); stA(BUF ^ 1, s, 3);
      stB(BUF ^ 1, s, 0, 0); stB(BUF ^ 1, s, 1, 0);
      stB(BUF ^ 1, s, 0, 1); stB(BUF ^ 1, s, 1, 1);
    }
    __builtin_amdgcn_s_barrier();
    asm volatile("s_waitcnt lgkmcnt(0)" ::: "memory");
    __builtin_amdgcn_sched_barrier(0);
    __builtin_amdgcn_s_setprio(1);
    #pragma unroll
    for (int mf = 0; mf < 2; ++mf)
      #pragma unroll
      for (int nf = 0; nf < 4; ++nf)
        #pragma unroll
        for (int kk = 0; kk < 2; ++kk)
          acc[mf][nf] = __builtin_amdgcn_mfma_f32_16x16x32_bf16(a01[mf][kk], bA[nf][kk], acc[mf][nf], 0, 0, 0);
    __builtin_amdgcn_s_setprio(0);
    __builtin_amdgcn_s_barrier();
    // ---- P2: read A mf2-3; wait old B01/B11 (issued 7 phases back)
    #pragma unroll
    for (int mf = 0; mf < 2; ++mf) {
      a23[mf][0] = *(const bf16x8*)&As[BUF][(wm * 64 + (mf + 2) * 16 + lm) * 64 + sw0];
      a23[mf][1] = *(const bf16x8*)&As[BUF][(wm * 64 + (mf + 2) * 16 + lm) * 64 + sw1];
    }
    if (st) { asm volatile("s_waitcnt vmcnt(8)" ::: "memory"); }
    else    { asm volatile("s_waitcnt vmcnt(0)" ::: "memory"); }
    __builtin_amdgcn_s_barrier();
    asm volatile("s_waitcnt lgkmcnt(0)" ::: "memory");
    __builtin_amdgcn_sched_barrier(0);
    __builtin_amdgcn_s_setprio(1);
    #pragma unroll
    for (int mf = 0; mf < 2; ++mf)
      #pragma unroll
      for (int nf = 0; nf < 4; ++nf)
        #pragma unroll
        for (int kk = 0; kk < 2; ++kk)
          acc[mf + 2][nf] = __builtin_amdgcn_mfma_f32_16x16x32_bf16(a23[mf][kk], bA[nf][kk], acc[mf + 2][nf], 0, 0, 0);
    __builtin_amdgcn_s_setprio(0);
    __builtin_amdgcn_s_barrier();
    // ---- P3: read B rows 64-127 of own half
    #pragma unroll
    for (int nf = 0; nf < 4; ++nf) {
      bB[nf][0] = *(const bf16x8*)&Bs[BUF][(wn * 128 + 64 + nf * 16 + lm) * 64 + sw0];
      bB[nf][1] = *(const bf16x8*)&Bs[BUF][(wn * 128 + 64 + nf * 16 + lm) * 64 + sw1];
    }
    __builtin_amdgcn_s_barrier();
    asm volatile("s_waitcnt lgkmcnt(0)" ::: "memory");
    __builtin_amdgcn_sched_barrier(0);
    __builtin_amdgcn_s_setprio(1);
    #pragma unroll
    for (int mf = 0; mf < 2; ++mf)
      #pragma unroll
      for (int nf = 0; nf < 4; ++nf)
        #pragma unroll
        for (int kk = 0; kk < 2; ++kk)
          acc[mf + 2][nf + 4] = __builtin_amdgcn_mfma_f32_16x16x32_bf16(a23[mf][kk], bB[nf][kk], acc[mf + 2][nf + 4], 0, 0, 0);
    __builtin_amdgcn_s_setprio(0);
    __builtin_amdgcn_s_barrier();
    // ---- P4: register-only MFMA (a01 x bB), then counted boundary wait
    __builtin_amdgcn_s_setprio(1);
    #pragma unroll
    for (int mf = 0; mf < 2; ++mf)
      #pragma unroll
      for (int nf = 0; nf < 4; ++nf)
        #pragma unroll
        for (int kk = 0; kk < 2; ++kk)
          acc[mf][nf + 4] = __builtin_amdgcn_mfma_f32_16x16x32_bf16(a01[mf][kk], bB[nf][kk], acc[mf][nf + 4], 0, 0, 0);
    __builtin_amdgcn_s_setprio(0);
    if (st) { asm volatile("s_waitcnt vmcnt(2)" ::: "memory"); }
    else    { asm volatile("s_waitcnt vmcnt(0)" ::: "memory"); }
    __builtin_amdgcn_s_barrier();
  };

  for (int th = 0; th < 18; ++th) {
    do_tile(2 * th, 0);
    do_tile(2 * th + 1, 1);
  }

  // epilogue: D row (o) = lg*4 + reg, col (n) = lm
  #pragma unroll
  for (int mf = 0; mf < 4; ++mf) {
    int o = wm * 64 + mf * 16 + lg * 4;
    float be0 = beff[b * 256 + o + 0];
    float be1 = beff[b * 256 + o + 1];
    float be2 = beff[b * 256 + o + 2];
    float be3 = beff[b * 256 + o + 3];
    #pragma unroll
    for (int nf = 0; nf < 8; ++nf) {
      int n = wn * 128 + nf * 16 + lm;
      int hh = h0 + (n >> 6), w = n & 63;
      float* op = out + (((size_t)(b * 256 + o)) * 64 + hh) * 64 + w;
      op[0]            = acc[mf][nf][0] + be0;
      op[4096]         = acc[mf][nf][1] + be1;
      op[2 * 4096]     = acc[mf][nf][2] + be2;
      op[3 * 4096]     = acc[mf][nf][3] + be3;
    }
  }
}

extern "C" void kernel_launch(void* const* d_in, const int* in_sizes, int n_in,
                              void* d_out, int out_size, void* d_ws, size_t ws_size,
                              hipStream_t stream) {
  const float* x        = (const float*)d_in[0];
  const float* time_emb = (const float*)d_in[1];
  const float* Wq = (const float*)d_in[2];
  const float* bq = (const float*)d_in[3];
  const float* Wk = (const float*)d_in[4];
  const float* bk = (const float*)d_in[5];
  const float* Wv = (const float*)d_in[6];
  const float* bv = (const float*)d_in[7];
  const float* Wm1 = (const float*)d_in[8];
  const float* bm1 = (const float*)d_in[9];
  const float* Wm2 = (const float*)d_in[10];
  const float* bm2 = (const float*)d_in[11];
  const float* Wc = (const float*)d_in[12];
  const float* bc = (const float*)d_in[13];
  const float* expert_w = (const float*)d_in[14];
  const float* expert_b = (const float*)d_in[15];
  float* out = (float*)d_out;

  char* ws = (char*)d_ws;
  float* rw   = (float*)(ws + 0);                        // 256 B
  float* beff = (float*)(ws + 1024);                     // 16 KB
  float* part = (float*)(ws + 20480);                    // 1 MB
  unsigned short* xTpad = (unsigned short*)(ws + 1069056);             // 35.7 MB
  unsigned short* wmix  = (unsigned short*)(ws + 1069056 + 35684352);  // 18.9 MB

  transpose_kernel<<<1056, 256, 0, stream>>>(x, xTpad, part);
  router_kernel<<<16, 512, 0, stream>>>(time_emb, part, Wq, bq, Wk, bk, Wv, bv,
                                        Wm1, bm1, Wm2, bm2, Wc, bc, expert_b, rw, beff);
  wmix_kernel<<<256, 256, 0, stream>>>(expert_w, rw, wmix);
  conv_kernel<<<256, 512, 0, stream>>>(xTpad, wmix, beff, out);
}

// Round 5
// 145.695 us; speedup vs baseline: 1.0475x; 1.0475x over previous
//
#include <hip/hip_runtime.h>

// B=16, C=256, O=256, H=W=64, T_DIM=512, E=4, K=3
typedef __bf16 bf16x8 __attribute__((ext_vector_type(8)));
typedef float f32x4 __attribute__((ext_vector_type(4)));

__device__ __forceinline__ unsigned short f2bf(float f) {
  union { float f; unsigned int u; } v;
  v.f = f;
  unsigned int r = v.u + 0x7FFFu + ((v.u >> 16) & 1u);  // RNE
  return (unsigned short)(r >> 16);
}

__device__ __forceinline__ void load_lds16(const void* g, void* l) {
  __builtin_amdgcn_global_load_lds(
      (__attribute__((address_space(1))) void*)(void*)g,
      (__attribute__((address_space(3))) void*)l, 16, 0, 0);
}

// ---------- transpose + pad + pooled partials ----------
__global__ void transpose_kernel(const float* __restrict__ x, unsigned short* __restrict__ xTpad,
                                 float* __restrict__ part) {
  int bid = blockIdx.x;
  int b = bid / 66, hp = bid % 66;
  unsigned short* rowbase = xTpad + ((size_t)(b * 66 + hp)) * 66 * 256;
  int t = threadIdx.x;
  if (hp == 0 || hp == 65) {
    uint4 z = make_uint4(0u, 0u, 0u, 0u);
    for (int i = t; i < 2112; i += 256) ((uint4*)rowbase)[i] = z;
    return;
  }
  int h = hp - 1;
  __shared__ unsigned short lds[64][264];
  __shared__ float psum[256];
  const float* xb = x + ((size_t)b * 256 * 64 + h) * 64;
  int lane = t & 63;
  #pragma unroll
  for (int g = 0; g < 16; ++g) {
    int c = g * 16 + (t >> 4);
    int w0 = (t & 15) * 4;
    float4 v = *(const float4*)&xb[(size_t)c * 4096 + w0];
    lds[w0 + 0][c] = f2bf(v.x);
    lds[w0 + 1][c] = f2bf(v.y);
    lds[w0 + 2][c] = f2bf(v.z);
    lds[w0 + 3][c] = f2bf(v.w);
    float s = v.x + v.y + v.z + v.w;
    s += __shfl_xor(s, 1); s += __shfl_xor(s, 2);
    s += __shfl_xor(s, 4); s += __shfl_xor(s, 8);
    if ((lane & 15) == 0) psum[c] = s;
  }
  __syncthreads();
  #pragma unroll
  for (int p = 0; p < 8; ++p) {
    int w = p * 8 + (t >> 5);
    int seg = t & 31;
    uint4 u = *(const uint4*)&lds[w][seg * 8];
    *(uint4*)&rowbase[(w + 1) * 256 + seg * 8] = u;
  }
  if (t < 64) {
    uint4 z = make_uint4(0u, 0u, 0u, 0u);
    int row = (t >> 5) ? 65 : 0;
    *(uint4*)&rowbase[row * 256 + (t & 31) * 8] = z;
  }
  if (t < 256) part[((size_t)b * 64 + h) * 256 + t] = psum[t];
}

// ---------- router (fp32 exact), 512 threads ----------
__global__ void router_kernel(
    const float* __restrict__ time_emb, const float* __restrict__ part,
    const float* __restrict__ Wq, const float* __restrict__ bq,
    const float* __restrict__ Wk, const float* __restrict__ bk,
    const float* __restrict__ Wv, const float* __restrict__ bv,
    const float* __restrict__ Wm1, const float* __restrict__ bm1,
    const float* __restrict__ Wm2, const float* __restrict__ bm2,
    const float* __restrict__ Wc, const float* __restrict__ bc,
    const float* __restrict__ expert_b,
    float* __restrict__ rw_out, float* __restrict__ beff_out) {
  int b = blockIdx.x, tid = threadIdx.x;
  int t = tid & 255;
  __shared__ float te[512], pl[256], qs[256], xa[256], m1s[64], xms[256], rws[4];
  te[tid] = time_emb[b * 512 + tid];
  if (tid < 256) {
    float s = 0.f;
    const float* pp = part + (size_t)b * 16384 + tid;
    for (int hh = 0; hh < 64; ++hh) s += pp[hh * 256];
    pl[tid] = s * (1.0f / 4096.0f);
  }
  __syncthreads();
  if (tid < 256) {
    float q = bq[t];
    const float4* wq4 = (const float4*)(Wq + (size_t)t * 512);
    #pragma unroll 4
    for (int i = 0; i < 128; ++i) {
      float4 w4 = wq4[i];
      q += w4.x * te[i*4] + w4.y * te[i*4+1] + w4.z * te[i*4+2] + w4.w * te[i*4+3];
    }
    qs[t] = q;
  } else {
    float k = bk[t], v = bv[t];
    const float4* wk4 = (const float4*)(Wk + (size_t)t * 256);
    const float4* wv4 = (const float4*)(Wv + (size_t)t * 256);
    #pragma unroll 4
    for (int i = 0; i < 64; ++i) {
      float4 a4 = wk4[i], b4 = wv4[i];
      float p0 = pl[i*4], p1 = pl[i*4+1], p2 = pl[i*4+2], p3 = pl[i*4+3];
      k += a4.x * p0 + a4.y * p1 + a4.z * p2 + a4.w * p3;
      v += b4.x * p0 + b4.y * p1 + b4.z * p2 + b4.w * p3;
    }
    xa[t] = k;
    xms[t] = v;
  }
  __syncthreads();
  if (tid < 256) {
    float k = xa[t], v = xms[t];
    float attn = 1.0f / (1.0f + expf(-(qs[t] * k)));
    qs[t] = v * attn;
  }
  __syncthreads();
  if (tid < 64) {
    float s = bm1[tid];
    const float4* w1 = (const float4*)(Wm1 + (size_t)tid * 256);
    #pragma unroll 4
    for (int i = 0; i < 64; ++i) {
      float4 w4 = w1[i];
      s += w4.x * qs[i*4] + w4.y * qs[i*4+1] + w4.z * qs[i*4+2] + w4.w * qs[i*4+3];
    }
    m1s[tid] = 0.5f * s * (1.0f + erff(s * 0.7071067811865476f));
  }
  __syncthreads();
  if (tid < 256) {
    float hsum = bm2[t];
    const float* w2 = Wm2 + (size_t)t * 64;
    for (int j = 0; j < 64; ++j) hsum += m1s[j] * w2[j];
    xms[t] = qs[t] + hsum;
  }
  __syncthreads();
  if (tid < 4) {
    float s = bc[tid];
    const float* wc = Wc + (size_t)tid * 256;
    for (int i = 0; i < 256; ++i) s += xms[i] * wc[i];
    float r = tanhf(s);
    rws[tid] = r;
    rw_out[b * 4 + tid] = r;
  }
  __syncthreads();
  if (tid < 256) {
    float be = 0.f;
    #pragma unroll
    for (int e = 0; e < 4; ++e) be += rws[e] * expert_b[e * 256 + t];
    beff_out[b * 256 + t] = be;
  }
}

// ---------- expert mix -> wmix[b][o][k], k = tap*256 + c ----------
__global__ void wmix_kernel(const float* __restrict__ ew, const float* __restrict__ rw,
                            unsigned short* __restrict__ wmix) {
  int o = blockIdx.x, t = threadIdx.x;
  __shared__ float lew[4][2304];
  __shared__ float rsh[64];
  if (t < 64) rsh[t] = rw[t];
  #pragma unroll
  for (int e = 0; e < 4; ++e) {
    const float* s = ew + ((size_t)e * 256 + o) * 2304;
    #pragma unroll
    for (int j = 0; j < 9; ++j) lew[e][j * 256 + t] = s[j * 256 + t];
  }
  __syncthreads();
  float wv[4][9];
  #pragma unroll
  for (int e = 0; e < 4; ++e)
    #pragma unroll
    for (int tt = 0; tt < 9; ++tt) wv[e][tt] = lew[e][t * 9 + tt];
  for (int b = 0; b < 16; ++b) {
    float r0 = rsh[b*4], r1 = rsh[b*4+1], r2 = rsh[b*4+2], r3 = rsh[b*4+3];
    unsigned short* wo = wmix + ((size_t)b * 256 + o) * 2304 + t;
    #pragma unroll
    for (int tt = 0; tt < 9; ++tt) {
      float m = r0 * wv[0][tt] + r1 * wv[1][tt] + r2 * wv[2][tt] + r3 * wv[3][tt];
      wo[tt * 256] = f2bf(m);
    }
  }
}

// ---------- conv: 256x256x2304 GEMM per sample ----------
// 8-phase / 2 K-tiles per iter. Half-tile ring: A[4][128x64], B[4][128x64];
// T0 = slots 0/1, T1 = slots 2/3. One half (2 gll) staged per phase at the
// earliest slot-free phase; vmcnt(4)@P4, vmcnt(8)@P8 only. K-order:
// t = kh*12 + cc*3 + kw (kw inner -> B rows L2-hit across the 3 kw taps).
__global__ __launch_bounds__(512, 2) void conv_kernel(
    const unsigned short* __restrict__ xT, const unsigned short* __restrict__ wmix,
    const float* __restrict__ beff, float* __restrict__ out) {
  __shared__ unsigned short As[4][8192];
  __shared__ unsigned short Bs[4][8192];
  int bid = blockIdx.x;
  int b = ((bid & 7) << 1) | ((bid >> 7) & 1);   // same b -> same XCD
  int nt = (bid >> 3) & 15;
  int h0 = nt << 2;
  int tid = threadIdx.x;
  int wid = tid >> 6, lane = tid & 63;
  int lm = lane & 15, lg = lane >> 4;
  int wm = wid >> 1, wn = wid & 1;   // 4M x 2N wave grid

  const unsigned short* wmb = wmix + (size_t)b * 256 * 2304;
  const unsigned short* xTb = xT + (size_t)b * 66 * 66 * 256;

  // staging lane constants (pre-swizzled source slot)
  int lr = lane >> 3;
  int slot_g = (lane & 7) ^ lr;
  int a_lane = lr * 2304 + slot_g * 8;
  int b_lane = lr * 256 + slot_g * 8;

  // read-side swizzled k-slot offsets (ushorts)
  int sw0 = ((0 + lg) ^ (lm & 7)) * 8;
  int sw1 = ((4 + lg) ^ (lm & 7)) * 8;

  // stA: stage A rows u*64..u*64+63 of tile (kh,cc,kw) into As[slot] rows (u&1)*64..
  auto stA = [&](int slot, int kh, int cc, int kw, int u) {
    const unsigned short* src =
        wmb + (size_t)(u * 64 + wid * 8) * 2304 + (kh * 3 + kw) * 256 + cc * 64 + a_lane;
    load_lds16(src, &As[slot][((u & 1) * 64 + wid * 8) * 64]);
  };
  // stB: stage B n-rows hg*64..hg*64+63 into Bs[slot] rows (hg&1)*64..
  auto stB = [&](int slot, int kh, int cc, int kw, int hg) {
    const unsigned short* src =
        xTb + (size_t)((h0 + hg + kh) * 66 + wid * 8 + kw) * 256 + cc * 64 + b_lane;
    load_lds16(src, &Bs[slot][((hg & 1) * 64 + wid * 8) * 64]);
  };

  f32x4 acc[4][8];
  #pragma unroll
  for (int mf = 0; mf < 4; ++mf)
    #pragma unroll
    for (int nf = 0; nf < 8; ++nf)
      acc[mf][nf] = (f32x4){0.f, 0.f, 0.f, 0.f};

  // frag address bases
  const int arow = (wm & 1) * 64;          // + mf*16 + lm
  const int aslot = wm >> 1;               // T0: aslot, T1: aslot+2
  const int bslot = wn;                    // T0: bslot, T1: bslot+2

  // prologue: tiles 0 (kh0,cc0,kw0) and 1 (kh0,cc0,kw1)
  stA(0, 0, 0, 0, 0); stA(0, 0, 0, 0, 1); stA(1, 0, 0, 0, 2); stA(1, 0, 0, 0, 3);
  stB(0, 0, 0, 0, 0); stB(0, 0, 0, 0, 1); stB(1, 0, 0, 0, 2); stB(1, 0, 0, 0, 3);
  stA(2, 0, 0, 1, 0); stA(2, 0, 0, 1, 1); stA(3, 0, 0, 1, 2); stA(3, 0, 0, 1, 3);
  stB(2, 0, 0, 1, 0); stB(2, 0, 0, 1, 1); stB(3, 0, 0, 1, 2); stB(3, 0, 0, 1, 3);
  asm volatile("s_waitcnt vmcnt(8)" ::: "memory");
  __builtin_amdgcn_s_barrier();

  for (int i = 0; i < 18; ++i) {
    bool st = (i < 17);
    int ta = 2 * i + 2, tb = 2 * i + 3;
    int kha = ta / 12, ra = ta % 12;
    int cca = ra / 3,  kwa = ra % 3;
    int khb = tb / 12, rb = tb % 12;
    int ccb = rb / 3,  kwb = rb % 3;

    bf16x8 a01[2][2], a23[2][2], bA[4][2], bB[4][2];

    // ================= T0 (slots A 0/1, B 0/1) =================
    // ---- P1: read a01 + bA ----
    #pragma unroll
    for (int mf = 0; mf < 2; ++mf) {
      a01[mf][0] = *(const bf16x8*)&As[aslot][(arow + mf * 16 + lm) * 64 + sw0];
      a01[mf][1] = *(const bf16x8*)&As[aslot][(arow + mf * 16 + lm) * 64 + sw1];
    }
    #pragma unroll
    for (int nf = 0; nf < 4; ++nf) {
      bA[nf][0] = *(const bf16x8*)&Bs[bslot][(nf * 16 + lm) * 64 + sw0];
      bA[nf][1] = *(const bf16x8*)&Bs[bslot][(nf * 16 + lm) * 64 + sw1];
    }
    __builtin_amdgcn_s_barrier();
    asm volatile("s_waitcnt lgkmcnt(0)" ::: "memory");
    __builtin_amdgcn_sched_barrier(0);
    __builtin_amdgcn_s_setprio(1);
    #pragma unroll
    for (int mf = 0; mf < 2; ++mf)
      #pragma unroll
      for (int nf = 0; nf < 4; ++nf)
        #pragma unroll
        for (int kk = 0; kk < 2; ++kk)
          acc[mf][nf] = __builtin_amdgcn_mfma_f32_16x16x32_bf16(a01[mf][kk], bA[nf][kk], acc[mf][nf], 0, 0, 0);
    __builtin_amdgcn_s_setprio(0);
    __builtin_amdgcn_s_barrier();
    // ---- P2: read a23 ----
    #pragma unroll
    for (int mf = 0; mf < 2; ++mf) {
      a23[mf][0] = *(const bf16x8*)&As[aslot][(arow + (mf + 2) * 16 + lm) * 64 + sw0];
      a23[mf][1] = *(const bf16x8*)&As[aslot][(arow + (mf + 2) * 16 + lm) * 64 + sw1];
    }
    __builtin_amdgcn_s_barrier();
    asm volatile("s_waitcnt lgkmcnt(0)" ::: "memory");
    __builtin_amdgcn_sched_barrier(0);
    __builtin_amdgcn_s_setprio(1);
    #pragma unroll
    for (int mf = 0; mf < 2; ++mf)
      #pragma unroll
      for (int nf = 0; nf < 4; ++nf)
        #pragma unroll
        for (int kk = 0; kk < 2; ++kk)
          acc[mf + 2][nf] = __builtin_amdgcn_mfma_f32_16x16x32_bf16(a23[mf][kk], bA[nf][kk], acc[mf + 2][nf], 0, 0, 0);
    __builtin_amdgcn_s_setprio(0);
    __builtin_amdgcn_s_barrier();
    // ---- P3: read bB; stage A-h0(ta) -> As[0] ----
    #pragma unroll
    for (int nf = 0; nf < 4; ++nf) {
      bB[nf][0] = *(const bf16x8*)&Bs[bslot][(64 + nf * 16 + lm) * 64 + sw0];
      bB[nf][1] = *(const bf16x8*)&Bs[bslot][(64 + nf * 16 + lm) * 64 + sw1];
    }
    if (st) { stA(0, kha, cca, kwa, 0); stA(0, kha, cca, kwa, 1); }
    __builtin_amdgcn_s_barrier();
    asm volatile("s_waitcnt lgkmcnt(0)" ::: "memory");
    __builtin_amdgcn_sched_barrier(0);
    __builtin_amdgcn_s_setprio(1);
    #pragma unroll
    for (int mf = 0; mf < 2; ++mf)
      #pragma unroll
      for (int nf = 0; nf < 4; ++nf)
        #pragma unroll
        for (int kk = 0; kk < 2; ++kk)
          acc[mf + 2][nf + 4] = __builtin_amdgcn_mfma_f32_16x16x32_bf16(a23[mf][kk], bB[nf][kk], acc[mf + 2][nf + 4], 0, 0, 0);
    __builtin_amdgcn_s_setprio(0);
    __builtin_amdgcn_s_barrier();
    // ---- P4: stage A-h1(ta) -> As[1]; reg-only MFMA; vmcnt(4) ----
    if (st) { stA(1, kha, cca, kwa, 2); stA(1, kha, cca, kwa, 3); }
    __builtin_amdgcn_s_setprio(1);
    #pragma unroll
    for (int mf = 0; mf < 2; ++mf)
      #pragma unroll
      for (int nf = 0; nf < 4; ++nf)
        #pragma unroll
        for (int kk = 0; kk < 2; ++kk)
          acc[mf][nf + 4] = __builtin_amdgcn_mfma_f32_16x16x32_bf16(a01[mf][kk], bB[nf][kk], acc[mf][nf + 4], 0, 0, 0);
    __builtin_amdgcn_s_setprio(0);
    if (st) { asm volatile("s_waitcnt vmcnt(4)" ::: "memory"); }
    else    { asm volatile("s_waitcnt vmcnt(0)" ::: "memory"); }
    __builtin_amdgcn_s_barrier();

    // ================= T1 (slots A 2/3, B 2/3) =================
    // ---- P5: read a01 + bA; stage B-h0(ta) -> Bs[0] ----
    #pragma unroll
    for (int mf = 0; mf < 2; ++mf) {
      a01[mf][0] = *(const bf16x8*)&As[aslot + 2][(arow + mf * 16 + lm) * 64 + sw0];
      a01[mf][1] = *(const bf16x8*)&As[aslot + 2][(arow + mf * 16 + lm) * 64 + sw1];
    }
    #pragma unroll
    for (int nf = 0; nf < 4; ++nf) {
      bA[nf][0] = *(const bf16x8*)&Bs[bslot + 2][(nf * 16 + lm) * 64 + sw0];
      bA[nf][1] = *(const bf16x8*)&Bs[bslot + 2][(nf * 16 + lm) * 64 + sw1];
    }
    if (st) { stB(0, kha, cca, kwa, 0); stB(0, kha, cca, kwa, 1); }
    __builtin_amdgcn_s_barrier();
    asm volatile("s_waitcnt lgkmcnt(0)" ::: "memory");
    __builtin_amdgcn_sched_barrier(0);
    __builtin_amdgcn_s_setprio(1);
    #pragma unroll
    for (int mf = 0; mf < 2; ++mf)
      #pragma unroll
      for (int nf = 0; nf < 4; ++nf)
        #pragma unroll
        for (int kk = 0; kk < 2; ++kk)
          acc[mf][nf] = __builtin_amdgcn_mfma_f32_16x16x32_bf16(a01[mf][kk], bA[nf][kk], acc[mf][nf], 0, 0, 0);
    __builtin_amdgcn_s_setprio(0);
    __builtin_amdgcn_s_barrier();
    // ---- P6: read a23; stage B-h1(ta) -> Bs[1] ----
    #pragma unroll
    for (int mf = 0; mf < 2; ++mf) {
      a23[mf][0] = *(const bf16x8*)&As[aslot + 2][(arow + (mf + 2) * 16 + lm) * 64 + sw0];
      a23[mf][1] = *(const bf16x8*)&As[aslot + 2][(arow + (mf + 2) * 16 + lm) * 64 + sw1];
    }
    if (st) { stB(1, kha, cca, kwa, 2); stB(1, kha, cca, kwa, 3); }
    __builtin_amdgcn_s_barrier();
    asm volatile("s_waitcnt lgkmcnt(0)" ::: "memory");
    __builtin_amdgcn_sched_barrier(0);
    __builtin_amdgcn_s_setprio(1);
    #pragma unroll
    for (int mf = 0; mf < 2; ++mf)
      #pragma unroll
      for (int nf = 0; nf < 4; ++nf)
        #pragma unroll
        for (int kk = 0; kk < 2; ++kk)
          acc[mf + 2][nf] = __builtin_amdgcn_mfma_f32_16x16x32_bf16(a23[mf][kk], bA[nf][kk], acc[mf + 2][nf], 0, 0, 0);
    __builtin_amdgcn_s_setprio(0);
    __builtin_amdgcn_s_barrier();
    // ---- P7: read bB; stage A(tb) -> As[2],As[3] ----
    #pragma unroll
    for (int nf = 0; nf < 4; ++nf) {
      bB[nf][0] = *(const bf16x8*)&Bs[bslot + 2][(64 + nf * 16 + lm) * 64 + sw0];
      bB[nf][1] = *(const bf16x8*)&Bs[bslot + 2][(64 + nf * 16 + lm) * 64 + sw1];
    }
    if (st) {
      stA(2, khb, ccb, kwb, 0); stA(2, khb, ccb, kwb, 1);
      stA(3, khb, ccb, kwb, 2); stA(3, khb, ccb, kwb, 3);
    }
    __builtin_amdgcn_s_barrier();
    asm volatile("s_waitcnt lgkmcnt(0)" ::: "memory");
    __builtin_amdgcn_sched_barrier(0);
    __builtin_amdgcn_s_setprio(1);
    #pragma unroll
    for (int mf = 0; mf < 2; ++mf)
      #pragma unroll
      for (int nf = 0; nf < 4; ++nf)
        #pragma unroll
        for (int kk = 0; kk < 2; ++kk)
          acc[mf + 2][nf + 4] = __builtin_amdgcn_mfma_f32_16x16x32_bf16(a23[mf][kk], bB[nf][kk], acc[mf + 2][nf + 4], 0, 0, 0);
    __builtin_amdgcn_s_setprio(0);
    __builtin_amdgcn_s_barrier();
    // ---- P8: stage B(tb) -> Bs[2],Bs[3]; reg-only MFMA; vmcnt(8) ----
    if (st) {
      stB(2, khb, ccb, kwb, 0); stB(2, khb, ccb, kwb, 1);
      stB(3, khb, ccb, kwb, 2); stB(3, khb, ccb, kwb, 3);
    }
    __builtin_amdgcn_s_setprio(1);
    #pragma unroll
    for (int mf = 0; mf < 2; ++mf)
      #pragma unroll
      for (int nf = 0; nf < 4; ++nf)
        #pragma unroll
        for (int kk = 0; kk < 2; ++kk)
          acc[mf][nf + 4] = __builtin_amdgcn_mfma_f32_16x16x32_bf16(a01[mf][kk], bB[nf][kk], acc[mf][nf + 4], 0, 0, 0);
    __builtin_amdgcn_s_setprio(0);
    if (st) { asm volatile("s_waitcnt vmcnt(8)" ::: "memory"); }
    else    { asm volatile("s_waitcnt vmcnt(0)" ::: "memory"); }
    __builtin_amdgcn_s_barrier();
  }

  // epilogue: D row (o) = lg*4 + reg, col (n) = lm
  #pragma unroll
  for (int mf = 0; mf < 4; ++mf) {
    int o = wm * 64 + mf * 16 + lg * 4;
    float be0 = beff[b * 256 + o + 0];
    float be1 = beff[b * 256 + o + 1];
    float be2 = beff[b * 256 + o + 2];
    float be3 = beff[b * 256 + o + 3];
    #pragma unroll
    for (int nf = 0; nf < 8; ++nf) {
      int n = wn * 128 + nf * 16 + lm;
      int hh = h0 + (n >> 6), w = n & 63;
      float* op = out + (((size_t)(b * 256 + o)) * 64 + hh) * 64 + w;
      op[0]            = acc[mf][nf][0] + be0;
      op[4096]         = acc[mf][nf][1] + be1;
      op[2 * 4096]     = acc[mf][nf][2] + be2;
      op[3 * 4096]     = acc[mf][nf][3] + be3;
    }
  }
}

extern "C" void kernel_launch(void* const* d_in, const int* in_sizes, int n_in,
                              void* d_out, int out_size, void* d_ws, size_t ws_size,
                              hipStream_t stream) {
  const float* x        = (const float*)d_in[0];
  const float* time_emb = (const float*)d_in[1];
  const float* Wq = (const float*)d_in[2];
  const float* bq = (const float*)d_in[3];
  const float* Wk = (const float*)d_in[4];
  const float* bk = (const float*)d_in[5];
  const float* Wv = (const float*)d_in[6];
  const float* bv = (const float*)d_in[7];
  const float* Wm1 = (const float*)d_in[8];
  const float* bm1 = (const float*)d_in[9];
  const float* Wm2 = (const float*)d_in[10];
  const float* bm2 = (const float*)d_in[11];
  const float* Wc = (const float*)d_in[12];
  const float* bc = (const float*)d_in[13];
  const float* expert_w = (const float*)d_in[14];
  const float* expert_b = (const float*)d_in[15];
  float* out = (float*)d_out;

  char* ws = (char*)d_ws;
  float* rw   = (float*)(ws + 0);
  float* beff = (float*)(ws + 1024);
  float* part = (float*)(ws + 20480);
  unsigned short* xTpad = (unsigned short*)(ws + 1069056);             // 35.7 MB
  unsigned short* wmix  = (unsigned short*)(ws + 1069056 + 35684352);  // 18.9 MB

  transpose_kernel<<<1056, 256, 0, stream>>>(x, xTpad, part);
  router_kernel<<<16, 512, 0, stream>>>(time_emb, part, Wq, bq, Wk, bk, Wv, bv,
                                        Wm1, bm1, Wm2, bm2, Wc, bc, expert_b, rw, beff);
  wmix_kernel<<<256, 256, 0, stream>>>(expert_w, rw, wmix);
  conv_kernel<<<256, 512, 0, stream>>>(xTpad, wmix, beff, out);
}